// Round 7
// baseline (140.594 us; speedup 1.0000x reference)
//
#include <hip/hip_runtime.h>
#include <math.h>

#define NC     10
#define NCP    12     // padded state stride (floats); 48B rows, 16B aligned
#define NM     128
#define NGEN   4
#define NPT    1023
#define NTREES 1024

#define RCPF(x) __builtin_amdgcn_rcpf(x)
#define WAVE_FENCE() __builtin_amdgcn_wave_barrier()

struct F12 { float4 a, b, c; };

__device__ __forceinline__ F12 ld12(const float* p) {
    F12 r; const float4* q = (const float4*)p;
    r.a = q[0]; r.b = q[1]; r.c = q[2]; return r;
}
__device__ __forceinline__ void unpack10(float* t, const F12& r) {
    t[0] = r.a.x; t[1] = r.a.y; t[2] = r.a.z; t[3] = r.a.w;
    t[4] = r.b.x; t[5] = r.b.y; t[6] = r.b.z; t[7] = r.b.w;
    t[8] = r.c.x; t[9] = r.c.y;
}
__device__ __forceinline__ void fma10(float* t, const F12& c, float s) {
    t[0] += c.a.x * s; t[1] += c.a.y * s; t[2] += c.a.z * s; t[3] += c.a.w * s;
    t[4] += c.b.x * s; t[5] += c.b.y * s; t[6] += c.b.z * s; t[7] += c.b.w * s;
    t[8] += c.c.x * s; t[9] += c.c.y * s;
}
__device__ __forceinline__ void mul10(float* t, const F12& r) {
    t[0] *= r.a.x; t[1] *= r.a.y; t[2] *= r.a.z; t[3] *= r.a.w;
    t[4] *= r.b.x; t[5] *= r.b.y; t[6] *= r.b.z; t[7] *= r.b.w;
    t[8] *= r.c.x; t[9] *= r.c.y;
}
__device__ __forceinline__ float sum10(const float* v) {
    return (((v[0] + v[1]) + (v[2] + v[3])) + ((v[4] + v[5]) + (v[6] + v[7]))) + (v[8] + v[9]);
}
__device__ __forceinline__ void add10(float* a, const float* b) {
    #pragma unroll
    for (int j = 0; j < NC; ++j) a[j] += b[j];
}

// 4 leaves (two independent pairs) -> two normalized pair-sums sa, sb
__device__ __forceinline__ float leaf_pair2(const float (*sBTpi)[NCP],
                                            int xa0, int xa1, int xb0, int xb1,
                                            float* sa, float* sb) {
    float a0[NC], a1[NC], b0[NC], b1[NC];
    unpack10(a0, ld12(&sBTpi[xa0][0]));
    unpack10(a1, ld12(&sBTpi[xa1][0]));
    unpack10(b0, ld12(&sBTpi[xb0][0]));
    unpack10(b1, ld12(&sBTpi[xb1][0]));
    const float nua0 = sum10(a0), nua1 = sum10(a1);
    const float nub0 = sum10(b0), nub1 = sum10(b1);
    const float ra0 = RCPF(nua0), ra1 = RCPF(nua1);
    const float rb0 = RCPF(nub0), rb1 = RCPF(nub1);
    #pragma unroll
    for (int j = 0; j < NC; ++j) {
        sa[j] = a0[j] * ra0 + a1[j] * ra1;
        sb[j] = b0[j] * rb0 + b1[j] * rb1;
    }
    return (__logf(nua0) + __logf(nua1)) + (__logf(nub0) + __logf(nub1));
}

// two independent internal nodes (register A); outputs may alias inputs
__device__ __forceinline__ float node_step2(const F12* acol, const float (*sBT)[NCP],
                                            const float* s0, const float* s1,
                                            int xv0, int xv1, float* o0, float* o1) {
    float t0[NC], t1[NC];
    #pragma unroll
    for (int i = 0; i < NC; ++i) { t0[i] = 0.f; t1[i] = 0.f; }
    #pragma unroll
    for (int j = 0; j < NC; ++j) {
        fma10(t0, acol[j], s0[j]);
        fma10(t1, acol[j], s1[j]);
    }
    mul10(t0, ld12(&sBT[xv0][0]));
    mul10(t1, ld12(&sBT[xv1][0]));
    const float nu0 = sum10(t0), nu1 = sum10(t1);
    const float r0 = RCPF(nu0), r1 = RCPF(nu1);
    #pragma unroll
    for (int j = 0; j < NC; ++j) { o0[j] = t0[j] * r0; o1[j] = t1[j] * r1; }
    return __logf(nu0) + __logf(nu1);
}

// single internal node (register A)
__device__ __forceinline__ float node_step(const F12* acol, const float (*sBT)[NCP],
                                           const float* sc, int xv, float* bout) {
    float t[NC];
    #pragma unroll
    for (int i = 0; i < NC; ++i) t[i] = 0.f;
    #pragma unroll
    for (int j = 0; j < NC; ++j) fma10(t, acol[j], sc[j]);
    mul10(t, ld12(&sBT[xv][0]));
    const float nu = sum10(t);
    const float r = RCPF(nu);
    #pragma unroll
    for (int j = 0; j < NC; ++j) bout[j] = t[j] * r;
    return __logf(nu);
}

// fused 2-level step on a SoA LDS buffer, in place (SIN == SOUT == stride).
// Dataflow forces all bin reads before the first bout write (every output
// depends on every input through nu0/nu1), and DS ops are in-order per wave,
// so in-place within one wave is safe.
template<int STRIDE>
__device__ __forceinline__ float fused_step_ip(const F12* acol, const float (*sBT)[NCP],
                                               float* buf, int l,
                                               int xc0, int xc1, int xp)
{
    float t0[NC], t1[NC];
    #pragma unroll
    for (int i = 0; i < NC; ++i) { t0[i] = 0.f; t1[i] = 0.f; }
    #pragma unroll
    for (int j = 0; j < NC; ++j) {
        float4 gv = *(const float4*)(buf + j * STRIDE + 4 * l);
        fma10(t0, acol[j], gv.x + gv.y);
        fma10(t1, acol[j], gv.z + gv.w);
    }
    mul10(t0, ld12(&sBT[xc0][0]));
    mul10(t1, ld12(&sBT[xc1][0]));
    const float nu0 = sum10(t0), nu1 = sum10(t1);
    const float r0 = RCPF(nu0), r1 = RCPF(nu1);
    float ll = __logf(nu0) + __logf(nu1);

    float tp[NC];
    #pragma unroll
    for (int i = 0; i < NC; ++i) tp[i] = 0.f;
    #pragma unroll
    for (int j = 0; j < NC; ++j)
        fma10(tp, acol[j], t0[j] * r0 + t1[j] * r1);
    mul10(tp, ld12(&sBT[xp][0]));
    const float nup = sum10(tp);
    ll += __logf(nup);
    const float rp = RCPF(nup);
    #pragma unroll
    for (int j = 0; j < NC; ++j) buf[j * STRIDE + l] = tp[j] * rp;
    return ll;
}

// ---------------- single fused kernel ----------------
// block = 256 threads = 4 (tree,g) units (one wave each, same g per block).
// Lane = one L6 subtree; left/right halves interleaved 2-wide for ILP.
// Tail (levels 5..0) is wave-local, in place in sB6 — no block barriers.
__global__ __launch_bounds__(256, 4)
void htmm_fused(const int* __restrict__ x,
                const float* __restrict__ A,
                const float* __restrict__ B,
                const float* __restrict__ Pi,
                float* __restrict__ out)
{
    __shared__ __align__(16) float sACol[NC][NCP];   // 0.5*smA[i][j], col-major
    __shared__ __align__(16) float sBT[NM][NCP];     // smB^T rows
    __shared__ __align__(16) float sBTpi[NM][NCP];   // pi ⊙ smB^T rows (leaves)
    __shared__ __align__(16) float sPiP[NCP];
    __shared__ __align__(16) float sB6[4][NC][64];   // per-unit SoA; tail runs in place

    const int bid = blockIdx.x;
    const int g = bid >> 8;
    const int treeBase = (bid & 255) * 4;
    const int tid = threadIdx.x;
    const int u = tid >> 6, lane = tid & 63;

    // ---- parameter softmaxes ----
    {
        for (int c = u; c < NC; c += 4) {
            float v0 = B[(c * NM + lane) * NGEN + g];
            float v1 = B[(c * NM + lane + 64) * NGEN + g];
            float mx = fmaxf(v0, v1);
            #pragma unroll
            for (int off = 32; off; off >>= 1) mx = fmaxf(mx, __shfl_xor(mx, off));
            float e0 = __expf(v0 - mx), e1 = __expf(v1 - mx);
            float s = e0 + e1;
            #pragma unroll
            for (int off = 32; off; off >>= 1) s += __shfl_xor(s, off);
            float rs = 1.f / s;
            sBT[lane][c]      = e0 * rs;
            sBT[lane + 64][c] = e1 * rs;
        }
        if (tid < NC) {   // A column softmax, 0.5 folded, col-major
            const int j = tid;
            float col[NC], mx = -1e30f;
            #pragma unroll
            for (int i = 0; i < NC; ++i) { col[i] = A[(i * NC + j) * NGEN + g]; mx = fmaxf(mx, col[i]); }
            float s = 0.f;
            #pragma unroll
            for (int i = 0; i < NC; ++i) { col[i] = __expf(col[i] - mx); s += col[i]; }
            const float rs = 0.5f / s;
            #pragma unroll
            for (int i = 0; i < NC; ++i) sACol[j][i] = col[i] * rs;
            sACol[j][10] = 0.f; sACol[j][11] = 0.f;
        }
        if (tid == 16) {  // Pi softmax
            float col[NC], mx = -1e30f;
            #pragma unroll
            for (int i = 0; i < NC; ++i) { col[i] = Pi[i * NGEN + g]; mx = fmaxf(mx, col[i]); }
            float s = 0.f;
            #pragma unroll
            for (int i = 0; i < NC; ++i) { col[i] = __expf(col[i] - mx); s += col[i]; }
            const float rs = 1.f / s;
            #pragma unroll
            for (int i = 0; i < NC; ++i) sPiP[i] = col[i] * rs;
            sPiP[10] = 0.f; sPiP[11] = 0.f;
        }
    }
    __syncthreads();
    if (tid < NM) {   // sBTpi[m][c] = pi[c] * sBT[m][c]
        F12 pi = ld12(sPiP);
        F12 r  = ld12(&sBT[tid][0]);
        sBTpi[tid][0] = pi.a.x * r.a.x; sBTpi[tid][1] = pi.a.y * r.a.y;
        sBTpi[tid][2] = pi.a.z * r.a.z; sBTpi[tid][3] = pi.a.w * r.a.w;
        sBTpi[tid][4] = pi.b.x * r.b.x; sBTpi[tid][5] = pi.b.y * r.b.y;
        sBTpi[tid][6] = pi.b.z * r.b.z; sBTpi[tid][7] = pi.b.w * r.b.w;
        sBTpi[tid][8] = pi.c.x * r.c.x; sBTpi[tid][9] = pi.c.y * r.c.y;
    }
    __syncthreads();

    // ---- hoist A into registers (one-time broadcast reads) ----
    F12 acol[NC];
    #pragma unroll
    for (int j = 0; j < NC; ++j) acol[j] = ld12(&sACol[j][0]);

    const int tree = treeBase + u;
    const int tb = tree * NPT;
    const int s = lane;

    // observation indices for this lane's subtree
    int xl[8];
    #pragma unroll
    for (int k = 0; k < 8; ++k) xl[k] = x[tb + 511 + 8 * s + k];
    int x8v[4];
    #pragma unroll
    for (int c = 0; c < 4; ++c) x8v[c] = x[tb + 255 + 4 * s + c];
    const int x7a = x[tb + 127 + 2 * s];
    const int x7b = x[tb + 128 + 2 * s];
    const int x6v = x[tb + 63 + s];

    float llacc = 0.f;
    float sL[NC], sR[NC], ba[NC], bb[NC];

    // interleaved halves: (left, right) processed pairwise for 2x ILP
    llacc += leaf_pair2(sBTpi, xl[0], xl[1], xl[4], xl[5], sL, sR);
    llacc += node_step2(acol, sBT, sL, sR, x8v[0], x8v[2], ba, bb);   // L8a, L8c
    llacc += leaf_pair2(sBTpi, xl[2], xl[3], xl[6], xl[7], sL, sR);
    llacc += node_step2(acol, sBT, sL, sR, x8v[1], x8v[3], sL, sR);   // L8b, L8d
    add10(sL, ba); add10(sR, bb);
    llacc += node_step2(acol, sBT, sL, sR, x7a, x7b, ba, bb);          // L7a, L7b
    #pragma unroll
    for (int j = 0; j < NC; ++j) sL[j] = ba[j] + bb[j];
    llacc += node_step(acol, sBT, sL, x6v, sL);                        // L6
    #pragma unroll
    for (int j = 0; j < NC; ++j) sB6[u][j][s] = sL[j];

    // ---- tail: levels 5..0, wave-local, in place in sB6 ----
    WAVE_FENCE();
    float lla = 0.f;
    if (lane < 16)
        lla = fused_step_ip<64>(acol, sBT, &sB6[u][0][0], lane,
                                x[tb + 31 + 2 * lane], x[tb + 32 + 2 * lane],
                                x[tb + 15 + lane]);
    llacc += lla;
    WAVE_FENCE();
    float llb = 0.f;
    if (lane < 4)
        llb = fused_step_ip<64>(acol, sBT, &sB6[u][0][0], lane,
                                x[tb + 7 + 2 * lane], x[tb + 8 + 2 * lane],
                                x[tb + 3 + lane]);
    llacc += llb;
    WAVE_FENCE();
    if (lane == 0)
        llacc += fused_step_ip<64>(acol, sBT, &sB6[u][0][0], 0,
                                   x[tb + 1], x[tb + 2], x[tb + 0]);

    // ---- full-wave reduce; lane 0 writes the unit's output ----
    #pragma unroll
    for (int off = 32; off; off >>= 1) llacc += __shfl_down(llacc, off);
    if (lane == 0) out[tree * NGEN + g] = llacc;
}

extern "C" void kernel_launch(void* const* d_in, const int* in_sizes, int n_in,
                              void* d_out, int out_size, void* d_ws, size_t ws_size,
                              hipStream_t stream) {
    const int*   x  = (const int*)d_in[0];
    const float* A  = (const float*)d_in[1];
    const float* B  = (const float*)d_in[2];
    const float* Pi = (const float*)d_in[3];
    float* out = (float*)d_out;
    htmm_fused<<<NTREES, 256, 0, stream>>>(x, A, B, Pi, out);
}

// Round 8
// 28.650 us; speedup vs baseline: 4.9074x; 4.9074x over previous
//
#include <hip/hip_runtime.h>
#include <math.h>

#define NC     10
#define NCP    12     // padded state stride (floats); 48B rows, 16B aligned
#define NM     128
#define NGEN   4
#define NPT    1023
#define NTREES 1024

#define RCPF(x) __builtin_amdgcn_rcpf(x)
#define WAVE_FENCE() __builtin_amdgcn_wave_barrier()

struct F12 { float4 a, b, c; };

__device__ __forceinline__ F12 ld12(const float* p) {
    F12 r; const float4* q = (const float4*)p;
    r.a = q[0]; r.b = q[1]; r.c = q[2]; return r;
}
__device__ __forceinline__ void unpack10(float* t, const F12& r) {
    t[0] = r.a.x; t[1] = r.a.y; t[2] = r.a.z; t[3] = r.a.w;
    t[4] = r.b.x; t[5] = r.b.y; t[6] = r.b.z; t[7] = r.b.w;
    t[8] = r.c.x; t[9] = r.c.y;
}
__device__ __forceinline__ void fma10(float* t, const F12& c, float s) {
    t[0] += c.a.x * s; t[1] += c.a.y * s; t[2] += c.a.z * s; t[3] += c.a.w * s;
    t[4] += c.b.x * s; t[5] += c.b.y * s; t[6] += c.b.z * s; t[7] += c.b.w * s;
    t[8] += c.c.x * s; t[9] += c.c.y * s;
}
__device__ __forceinline__ void mul10(float* t, const F12& r) {
    t[0] *= r.a.x; t[1] *= r.a.y; t[2] *= r.a.z; t[3] *= r.a.w;
    t[4] *= r.b.x; t[5] *= r.b.y; t[6] *= r.b.z; t[7] *= r.b.w;
    t[8] *= r.c.x; t[9] *= r.c.y;
}
__device__ __forceinline__ float sum10(const float* v) {
    return (((v[0] + v[1]) + (v[2] + v[3])) + ((v[4] + v[5]) + (v[6] + v[7]))) + (v[8] + v[9]);
}

// two leaves -> normalized-pair-sum sc[j]; returns log nu0 + log nu1
__device__ __forceinline__ float leaf_pair(const float (*sBTpi)[NCP], int xv0, int xv1, float* sc) {
    float b0[NC], b1[NC];
    unpack10(b0, ld12(&sBTpi[xv0][0]));
    unpack10(b1, ld12(&sBTpi[xv1][0]));
    const float nu0 = sum10(b0), nu1 = sum10(b1);
    const float r0 = RCPF(nu0), r1 = RCPF(nu1);
    #pragma unroll
    for (int j = 0; j < NC; ++j) sc[j] = b0[j] * r0 + b1[j] * r1;
    return __logf(nu0) + __logf(nu1);
}

// one internal node from a pair-sum vector sc (register A): bout = normalized beta
__device__ __forceinline__ float node_step(const F12* acol, const float (*sBT)[NCP],
                                           const float* sc, int xv, float* bout) {
    float t[NC];
    #pragma unroll
    for (int i = 0; i < NC; ++i) t[i] = 0.f;
    #pragma unroll
    for (int j = 0; j < NC; ++j) fma10(t, acol[j], sc[j]);
    mul10(t, ld12(&sBT[xv][0]));
    const float nu = sum10(t);
    const float r = RCPF(nu);
    #pragma unroll
    for (int j = 0; j < NC; ++j) bout[j] = t[j] * r;
    return __logf(nu);
}

// fused 2-level step on a SoA LDS buffer, in place (stride 64).
// All reads precede the single write in program order, and the whole wave
// executes the same instruction stream in lockstep, so in-place is safe
// (verified: R7 passed correctness with this tail).
__device__ __forceinline__ float fused_step_ip(const F12* acol, const float (*sBT)[NCP],
                                               float* buf, int l,
                                               int xc0, int xc1, int xp)
{
    float t0[NC], t1[NC];
    #pragma unroll
    for (int i = 0; i < NC; ++i) { t0[i] = 0.f; t1[i] = 0.f; }
    #pragma unroll
    for (int j = 0; j < NC; ++j) {
        float4 gv = *(const float4*)(buf + j * 64 + 4 * l);
        fma10(t0, acol[j], gv.x + gv.y);
        fma10(t1, acol[j], gv.z + gv.w);
    }
    mul10(t0, ld12(&sBT[xc0][0]));
    mul10(t1, ld12(&sBT[xc1][0]));
    const float nu0 = sum10(t0), nu1 = sum10(t1);
    const float r0 = RCPF(nu0), r1 = RCPF(nu1);
    float ll = __logf(nu0) + __logf(nu1);

    float tp[NC];
    #pragma unroll
    for (int i = 0; i < NC; ++i) tp[i] = 0.f;
    #pragma unroll
    for (int j = 0; j < NC; ++j)
        fma10(tp, acol[j], t0[j] * r0 + t1[j] * r1);
    mul10(tp, ld12(&sBT[xp][0]));
    const float nup = sum10(tp);
    ll += __logf(nup);
    const float rp = RCPF(nup);
    #pragma unroll
    for (int j = 0; j < NC; ++j) buf[j * 64 + l] = tp[j] * rp;
    return ll;
}

// ---------------- single fused kernel ----------------
// block = 256 threads = 4 (tree,g) units (one wave each, same g per block).
// Lane = one L6 subtree computed SEQUENTIALLY in registers (VGPR ~80, no spill;
// the 2-wide interleave + launch_bounds cap spilled to scratch in R7 — do not
// reintroduce without checking VGPR_Count stays <= 96).
// Tail (levels 5..0) is wave-local, in place in sB6 — no block barriers.
__global__ __launch_bounds__(256)
void htmm_fused(const int* __restrict__ x,
                const float* __restrict__ A,
                const float* __restrict__ B,
                const float* __restrict__ Pi,
                float* __restrict__ out)
{
    __shared__ __align__(16) float sACol[NC][NCP];   // 0.5*smA[i][j], col-major
    __shared__ __align__(16) float sBT[NM][NCP];     // smB^T rows
    __shared__ __align__(16) float sBTpi[NM][NCP];   // pi ⊙ smB^T rows (leaves)
    __shared__ __align__(16) float sPiP[NCP];
    __shared__ __align__(16) float sB6[4][NC][64];   // per-unit SoA; tail runs in place

    const int bid = blockIdx.x;
    const int g = bid >> 8;
    const int treeBase = (bid & 255) * 4;
    const int tid = threadIdx.x;
    const int u = tid >> 6, lane = tid & 63;

    // ---- parameter softmaxes ----
    {
        for (int c = u; c < NC; c += 4) {
            float v0 = B[(c * NM + lane) * NGEN + g];
            float v1 = B[(c * NM + lane + 64) * NGEN + g];
            float mx = fmaxf(v0, v1);
            #pragma unroll
            for (int off = 32; off; off >>= 1) mx = fmaxf(mx, __shfl_xor(mx, off));
            float e0 = __expf(v0 - mx), e1 = __expf(v1 - mx);
            float s = e0 + e1;
            #pragma unroll
            for (int off = 32; off; off >>= 1) s += __shfl_xor(s, off);
            float rs = 1.f / s;
            sBT[lane][c]      = e0 * rs;
            sBT[lane + 64][c] = e1 * rs;
        }
        if (tid < NC) {   // A column softmax, 0.5 folded, col-major
            const int j = tid;
            float col[NC], mx = -1e30f;
            #pragma unroll
            for (int i = 0; i < NC; ++i) { col[i] = A[(i * NC + j) * NGEN + g]; mx = fmaxf(mx, col[i]); }
            float s = 0.f;
            #pragma unroll
            for (int i = 0; i < NC; ++i) { col[i] = __expf(col[i] - mx); s += col[i]; }
            const float rs = 0.5f / s;
            #pragma unroll
            for (int i = 0; i < NC; ++i) sACol[j][i] = col[i] * rs;
            sACol[j][10] = 0.f; sACol[j][11] = 0.f;
        }
        if (tid == 16) {  // Pi softmax
            float col[NC], mx = -1e30f;
            #pragma unroll
            for (int i = 0; i < NC; ++i) { col[i] = Pi[i * NGEN + g]; mx = fmaxf(mx, col[i]); }
            float s = 0.f;
            #pragma unroll
            for (int i = 0; i < NC; ++i) { col[i] = __expf(col[i] - mx); s += col[i]; }
            const float rs = 1.f / s;
            #pragma unroll
            for (int i = 0; i < NC; ++i) sPiP[i] = col[i] * rs;
            sPiP[10] = 0.f; sPiP[11] = 0.f;
        }
    }
    __syncthreads();
    if (tid < NM) {   // sBTpi[m][c] = pi[c] * sBT[m][c]
        F12 pi = ld12(sPiP);
        F12 r  = ld12(&sBT[tid][0]);
        sBTpi[tid][0] = pi.a.x * r.a.x; sBTpi[tid][1] = pi.a.y * r.a.y;
        sBTpi[tid][2] = pi.a.z * r.a.z; sBTpi[tid][3] = pi.a.w * r.a.w;
        sBTpi[tid][4] = pi.b.x * r.b.x; sBTpi[tid][5] = pi.b.y * r.b.y;
        sBTpi[tid][6] = pi.b.z * r.b.z; sBTpi[tid][7] = pi.b.w * r.b.w;
        sBTpi[tid][8] = pi.c.x * r.c.x; sBTpi[tid][9] = pi.c.y * r.c.y;
    }
    __syncthreads();

    // ---- hoist A into registers (one-time broadcast reads) ----
    F12 acol[NC];
    #pragma unroll
    for (int j = 0; j < NC; ++j) acol[j] = ld12(&sACol[j][0]);

    const int tree = treeBase + u;
    const int tb = tree * NPT;
    const int s = lane;

    // observation indices for this lane's subtree
    int xl[8];
    #pragma unroll
    for (int k = 0; k < 8; ++k) xl[k] = x[tb + 511 + 8 * s + k];
    int x8v[4];
    #pragma unroll
    for (int c = 0; c < 4; ++c) x8v[c] = x[tb + 255 + 4 * s + c];
    const int x7a = x[tb + 127 + 2 * s];
    const int x7b = x[tb + 128 + 2 * s];
    const int x6v = x[tb + 63 + s];

    float llacc = 0.f;
    float sc[NC], ba[NC], bb[NC], b7a[NC], b7b[NC];

    // left half: leaves 0-3 -> L8 nodes 0,1 -> L7 node a
    llacc += leaf_pair(sBTpi, xl[0], xl[1], sc);
    llacc += node_step(acol, sBT, sc, x8v[0], ba);
    llacc += leaf_pair(sBTpi, xl[2], xl[3], sc);
    llacc += node_step(acol, sBT, sc, x8v[1], bb);
    #pragma unroll
    for (int j = 0; j < NC; ++j) sc[j] = ba[j] + bb[j];
    llacc += node_step(acol, sBT, sc, x7a, b7a);

    // right half: leaves 4-7 -> L8 nodes 2,3 -> L7 node b
    llacc += leaf_pair(sBTpi, xl[4], xl[5], sc);
    llacc += node_step(acol, sBT, sc, x8v[2], ba);
    llacc += leaf_pair(sBTpi, xl[6], xl[7], sc);
    llacc += node_step(acol, sBT, sc, x8v[3], bb);
    #pragma unroll
    for (int j = 0; j < NC; ++j) sc[j] = ba[j] + bb[j];
    llacc += node_step(acol, sBT, sc, x7b, b7b);

    // L6 node
    #pragma unroll
    for (int j = 0; j < NC; ++j) sc[j] = b7a[j] + b7b[j];
    llacc += node_step(acol, sBT, sc, x6v, ba);
    #pragma unroll
    for (int j = 0; j < NC; ++j) sB6[u][j][s] = ba[j];   // SoA, lane-contiguous

    // ---- tail: levels 5..0, wave-local, in place in sB6 ----
    WAVE_FENCE();
    float lla = 0.f;
    if (lane < 16)
        lla = fused_step_ip(acol, sBT, &sB6[u][0][0], lane,
                            x[tb + 31 + 2 * lane], x[tb + 32 + 2 * lane],
                            x[tb + 15 + lane]);
    llacc += lla;
    WAVE_FENCE();
    float llb = 0.f;
    if (lane < 4)
        llb = fused_step_ip(acol, sBT, &sB6[u][0][0], lane,
                            x[tb + 7 + 2 * lane], x[tb + 8 + 2 * lane],
                            x[tb + 3 + lane]);
    llacc += llb;
    WAVE_FENCE();
    if (lane == 0)
        llacc += fused_step_ip(acol, sBT, &sB6[u][0][0], 0,
                               x[tb + 1], x[tb + 2], x[tb + 0]);

    // ---- full-wave reduce; lane 0 writes the unit's output ----
    #pragma unroll
    for (int off = 32; off; off >>= 1) llacc += __shfl_down(llacc, off);
    if (lane == 0) out[tree * NGEN + g] = llacc;
}

extern "C" void kernel_launch(void* const* d_in, const int* in_sizes, int n_in,
                              void* d_out, int out_size, void* d_ws, size_t ws_size,
                              hipStream_t stream) {
    const int*   x  = (const int*)d_in[0];
    const float* A  = (const float*)d_in[1];
    const float* B  = (const float*)d_in[2];
    const float* Pi = (const float*)d_in[3];
    float* out = (float*)d_out;
    htmm_fused<<<NTREES, 256, 0, stream>>>(x, A, B, Pi, out);
}

// Round 9
// 28.549 us; speedup vs baseline: 4.9246x; 1.0035x over previous
//
#include <hip/hip_runtime.h>
#include <math.h>

#define NC     10
#define NCP    12     // padded state stride (floats); 48B rows, 16B aligned
#define NM     128
#define NGEN   4
#define NPT    1023
#define NTREES 1024

#define RCPF(x) __builtin_amdgcn_rcpf(x)
#define WAVE_FENCE() __builtin_amdgcn_wave_barrier()

struct F12 { float4 a, b, c; };

__device__ __forceinline__ F12 ld12(const float* p) {
    F12 r; const float4* q = (const float4*)p;
    r.a = q[0]; r.b = q[1]; r.c = q[2]; return r;
}
__device__ __forceinline__ void unpack10(float* t, const F12& r) {
    t[0] = r.a.x; t[1] = r.a.y; t[2] = r.a.z; t[3] = r.a.w;
    t[4] = r.b.x; t[5] = r.b.y; t[6] = r.b.z; t[7] = r.b.w;
    t[8] = r.c.x; t[9] = r.c.y;
}
__device__ __forceinline__ void fma10(float* t, const F12& c, float s) {
    t[0] += c.a.x * s; t[1] += c.a.y * s; t[2] += c.a.z * s; t[3] += c.a.w * s;
    t[4] += c.b.x * s; t[5] += c.b.y * s; t[6] += c.b.z * s; t[7] += c.b.w * s;
    t[8] += c.c.x * s; t[9] += c.c.y * s;
}
__device__ __forceinline__ void mul10(float* t, const F12& r) {
    t[0] *= r.a.x; t[1] *= r.a.y; t[2] *= r.a.z; t[3] *= r.a.w;
    t[4] *= r.b.x; t[5] *= r.b.y; t[6] *= r.b.z; t[7] *= r.b.w;
    t[8] *= r.c.x; t[9] *= r.c.y;
}
__device__ __forceinline__ float sum10(const float* v) {
    return (((v[0] + v[1]) + (v[2] + v[3])) + ((v[4] + v[5]) + (v[6] + v[7]))) + (v[8] + v[9]);
}
__device__ __forceinline__ void add10(float* a, const float* b) {
    #pragma unroll
    for (int j = 0; j < NC; ++j) a[j] += b[j];
}

// 4 leaves (two independent pairs) -> two normalized pair-sums sa, sb.
// 4 LDS row loads issued together (latency overlap), 4 independent sum/rcp/log chains.
__device__ __forceinline__ float leaf_pair2(const float (*sBTpi)[NCP],
                                            int xa0, int xa1, int xb0, int xb1,
                                            float* sa, float* sb) {
    float a0[NC], a1[NC], b0[NC], b1[NC];
    unpack10(a0, ld12(&sBTpi[xa0][0]));
    unpack10(a1, ld12(&sBTpi[xa1][0]));
    unpack10(b0, ld12(&sBTpi[xb0][0]));
    unpack10(b1, ld12(&sBTpi[xb1][0]));
    const float nua0 = sum10(a0), nua1 = sum10(a1);
    const float nub0 = sum10(b0), nub1 = sum10(b1);
    const float ra0 = RCPF(nua0), ra1 = RCPF(nua1);
    const float rb0 = RCPF(nub0), rb1 = RCPF(nub1);
    #pragma unroll
    for (int j = 0; j < NC; ++j) {
        sa[j] = a0[j] * ra0 + a1[j] * ra1;
        sb[j] = b0[j] * rb0 + b1[j] * rb1;
    }
    return (__logf(nua0) + __logf(nua1)) + (__logf(nub0) + __logf(nub1));
}

// two independent internal nodes (register A); outputs may alias inputs
__device__ __forceinline__ float node_step2(const F12* acol, const float (*sBT)[NCP],
                                            const float* s0, const float* s1,
                                            int xv0, int xv1, float* o0, float* o1) {
    float t0[NC], t1[NC];
    #pragma unroll
    for (int i = 0; i < NC; ++i) { t0[i] = 0.f; t1[i] = 0.f; }
    #pragma unroll
    for (int j = 0; j < NC; ++j) {
        fma10(t0, acol[j], s0[j]);
        fma10(t1, acol[j], s1[j]);
    }
    mul10(t0, ld12(&sBT[xv0][0]));
    mul10(t1, ld12(&sBT[xv1][0]));
    const float nu0 = sum10(t0), nu1 = sum10(t1);
    const float r0 = RCPF(nu0), r1 = RCPF(nu1);
    #pragma unroll
    for (int j = 0; j < NC; ++j) { o0[j] = t0[j] * r0; o1[j] = t1[j] * r1; }
    return __logf(nu0) + __logf(nu1);
}

// single internal node (register A)
__device__ __forceinline__ float node_step(const F12* acol, const float (*sBT)[NCP],
                                           const float* sc, int xv, float* bout) {
    float t[NC];
    #pragma unroll
    for (int i = 0; i < NC; ++i) t[i] = 0.f;
    #pragma unroll
    for (int j = 0; j < NC; ++j) fma10(t, acol[j], sc[j]);
    mul10(t, ld12(&sBT[xv][0]));
    const float nu = sum10(t);
    const float r = RCPF(nu);
    #pragma unroll
    for (int j = 0; j < NC; ++j) bout[j] = t[j] * r;
    return __logf(nu);
}

// fused 2-level step on a SoA LDS buffer, in place (stride 64).
// All reads precede the single write in program order; DS ops are in-order
// per wave, so in-place within one wave is safe (verified R7/R8 correctness).
__device__ __forceinline__ float fused_step_ip(const F12* acol, const float (*sBT)[NCP],
                                               float* buf, int l,
                                               int xc0, int xc1, int xp)
{
    float t0[NC], t1[NC];
    #pragma unroll
    for (int i = 0; i < NC; ++i) { t0[i] = 0.f; t1[i] = 0.f; }
    #pragma unroll
    for (int j = 0; j < NC; ++j) {
        float4 gv = *(const float4*)(buf + j * 64 + 4 * l);
        fma10(t0, acol[j], gv.x + gv.y);
        fma10(t1, acol[j], gv.z + gv.w);
    }
    mul10(t0, ld12(&sBT[xc0][0]));
    mul10(t1, ld12(&sBT[xc1][0]));
    const float nu0 = sum10(t0), nu1 = sum10(t1);
    const float r0 = RCPF(nu0), r1 = RCPF(nu1);
    float ll = __logf(nu0) + __logf(nu1);

    float tp[NC];
    #pragma unroll
    for (int i = 0; i < NC; ++i) tp[i] = 0.f;
    #pragma unroll
    for (int j = 0; j < NC; ++j)
        fma10(tp, acol[j], t0[j] * r0 + t1[j] * r1);
    mul10(tp, ld12(&sBT[xp][0]));
    const float nup = sum10(tp);
    ll += __logf(nup);
    const float rp = RCPF(nup);
    #pragma unroll
    for (int j = 0; j < NC; ++j) buf[j * 64 + l] = tp[j] * rp;
    return ll;
}

// ---------------- single fused kernel ----------------
// block = 256 threads = 4 (tree,g) units (one wave each, same g per block).
// Lane = one L6 subtree; left/right halves interleaved 2-wide for ILP.
// NOTE: NO min-occupancy in __launch_bounds__ — R7 showed that (256,4) caps
// VGPR at 64 and spills 600 MB to scratch. Interleave needs ~110-125 VGPR,
// same 4-waves/SIMD occupancy tier as the sequential version's 80.
// Tail (levels 5..0) is wave-local, in place in sB6 — no block barriers.
__global__ __launch_bounds__(256)
void htmm_fused(const int* __restrict__ x,
                const float* __restrict__ A,
                const float* __restrict__ B,
                const float* __restrict__ Pi,
                float* __restrict__ out)
{
    __shared__ __align__(16) float sACol[NC][NCP];   // 0.5*smA[i][j], col-major
    __shared__ __align__(16) float sBT[NM][NCP];     // smB^T rows
    __shared__ __align__(16) float sBTpi[NM][NCP];   // pi ⊙ smB^T rows (leaves)
    __shared__ __align__(16) float sPiP[NCP];
    __shared__ __align__(16) float sB6[4][NC][64];   // per-unit SoA; tail runs in place

    const int bid = blockIdx.x;
    const int g = bid >> 8;
    const int treeBase = (bid & 255) * 4;
    const int tid = threadIdx.x;
    const int u = tid >> 6, lane = tid & 63;

    // ---- parameter softmaxes ----
    {
        for (int c = u; c < NC; c += 4) {
            float v0 = B[(c * NM + lane) * NGEN + g];
            float v1 = B[(c * NM + lane + 64) * NGEN + g];
            float mx = fmaxf(v0, v1);
            #pragma unroll
            for (int off = 32; off; off >>= 1) mx = fmaxf(mx, __shfl_xor(mx, off));
            float e0 = __expf(v0 - mx), e1 = __expf(v1 - mx);
            float s = e0 + e1;
            #pragma unroll
            for (int off = 32; off; off >>= 1) s += __shfl_xor(s, off);
            float rs = 1.f / s;
            sBT[lane][c]      = e0 * rs;
            sBT[lane + 64][c] = e1 * rs;
        }
        if (tid < NC) {   // A column softmax, 0.5 folded, col-major
            const int j = tid;
            float col[NC], mx = -1e30f;
            #pragma unroll
            for (int i = 0; i < NC; ++i) { col[i] = A[(i * NC + j) * NGEN + g]; mx = fmaxf(mx, col[i]); }
            float s = 0.f;
            #pragma unroll
            for (int i = 0; i < NC; ++i) { col[i] = __expf(col[i] - mx); s += col[i]; }
            const float rs = 0.5f / s;
            #pragma unroll
            for (int i = 0; i < NC; ++i) sACol[j][i] = col[i] * rs;
            sACol[j][10] = 0.f; sACol[j][11] = 0.f;
        }
        if (tid == 16) {  // Pi softmax
            float col[NC], mx = -1e30f;
            #pragma unroll
            for (int i = 0; i < NC; ++i) { col[i] = Pi[i * NGEN + g]; mx = fmaxf(mx, col[i]); }
            float s = 0.f;
            #pragma unroll
            for (int i = 0; i < NC; ++i) { col[i] = __expf(col[i] - mx); s += col[i]; }
            const float rs = 1.f / s;
            #pragma unroll
            for (int i = 0; i < NC; ++i) sPiP[i] = col[i] * rs;
            sPiP[10] = 0.f; sPiP[11] = 0.f;
        }
    }
    __syncthreads();
    if (tid < NM) {   // sBTpi[m][c] = pi[c] * sBT[m][c]
        F12 pi = ld12(sPiP);
        F12 r  = ld12(&sBT[tid][0]);
        sBTpi[tid][0] = pi.a.x * r.a.x; sBTpi[tid][1] = pi.a.y * r.a.y;
        sBTpi[tid][2] = pi.a.z * r.a.z; sBTpi[tid][3] = pi.a.w * r.a.w;
        sBTpi[tid][4] = pi.b.x * r.b.x; sBTpi[tid][5] = pi.b.y * r.b.y;
        sBTpi[tid][6] = pi.b.z * r.b.z; sBTpi[tid][7] = pi.b.w * r.b.w;
        sBTpi[tid][8] = pi.c.x * r.c.x; sBTpi[tid][9] = pi.c.y * r.c.y;
    }
    __syncthreads();

    // ---- hoist A into registers (one-time broadcast reads) ----
    F12 acol[NC];
    #pragma unroll
    for (int j = 0; j < NC; ++j) acol[j] = ld12(&sACol[j][0]);

    const int tree = treeBase + u;
    const int tb = tree * NPT;
    const int s = lane;

    // observation indices for this lane's subtree
    int xl[8];
    #pragma unroll
    for (int k = 0; k < 8; ++k) xl[k] = x[tb + 511 + 8 * s + k];
    int x8v[4];
    #pragma unroll
    for (int c = 0; c < 4; ++c) x8v[c] = x[tb + 255 + 4 * s + c];
    const int x7a = x[tb + 127 + 2 * s];
    const int x7b = x[tb + 128 + 2 * s];
    const int x6v = x[tb + 63 + s];

    float llacc = 0.f;
    float sL[NC], sR[NC], ba[NC], bb[NC];

    // interleaved halves: (left, right) processed pairwise for 2x ILP
    llacc += leaf_pair2(sBTpi, xl[0], xl[1], xl[4], xl[5], sL, sR);
    llacc += node_step2(acol, sBT, sL, sR, x8v[0], x8v[2], ba, bb);   // L8a, L8c
    llacc += leaf_pair2(sBTpi, xl[2], xl[3], xl[6], xl[7], sL, sR);
    llacc += node_step2(acol, sBT, sL, sR, x8v[1], x8v[3], sL, sR);   // L8b, L8d
    add10(sL, ba); add10(sR, bb);
    llacc += node_step2(acol, sBT, sL, sR, x7a, x7b, ba, bb);          // L7a, L7b
    #pragma unroll
    for (int j = 0; j < NC; ++j) sL[j] = ba[j] + bb[j];
    llacc += node_step(acol, sBT, sL, x6v, sL);                        // L6
    #pragma unroll
    for (int j = 0; j < NC; ++j) sB6[u][j][s] = sL[j];

    // ---- tail: levels 5..0, wave-local, in place in sB6 ----
    WAVE_FENCE();
    float lla = 0.f;
    if (lane < 16)
        lla = fused_step_ip(acol, sBT, &sB6[u][0][0], lane,
                            x[tb + 31 + 2 * lane], x[tb + 32 + 2 * lane],
                            x[tb + 15 + lane]);
    llacc += lla;
    WAVE_FENCE();
    float llb = 0.f;
    if (lane < 4)
        llb = fused_step_ip(acol, sBT, &sB6[u][0][0], lane,
                            x[tb + 7 + 2 * lane], x[tb + 8 + 2 * lane],
                            x[tb + 3 + lane]);
    llacc += llb;
    WAVE_FENCE();
    if (lane == 0)
        llacc += fused_step_ip(acol, sBT, &sB6[u][0][0], 0,
                               x[tb + 1], x[tb + 2], x[tb + 0]);

    // ---- full-wave reduce; lane 0 writes the unit's output ----
    #pragma unroll
    for (int off = 32; off; off >>= 1) llacc += __shfl_down(llacc, off);
    if (lane == 0) out[tree * NGEN + g] = llacc;
}

extern "C" void kernel_launch(void* const* d_in, const int* in_sizes, int n_in,
                              void* d_out, int out_size, void* d_ws, size_t ws_size,
                              hipStream_t stream) {
    const int*   x  = (const int*)d_in[0];
    const float* A  = (const float*)d_in[1];
    const float* B  = (const float*)d_in[2];
    const float* Pi = (const float*)d_in[3];
    float* out = (float*)d_out;
    htmm_fused<<<NTREES, 256, 0, stream>>>(x, A, B, Pi, out);
}